// Round 5
// baseline (309.366 us; speedup 1.0000x reference)
//
#include <hip/hip_runtime.h>
#include <hip/hip_bf16.h>

typedef unsigned short u16;
typedef __attribute__((ext_vector_type(8))) __bf16 bf8v;
typedef __attribute__((ext_vector_type(4))) float f32x4;
typedef __attribute__((ext_vector_type(4))) unsigned uint4v;

#define B_ 4
#define N_ 16384
#define M_ 16384
#define K_ 16
#define C_ 64
#define O_ 64
#define G_ 8

__device__ __forceinline__ float bf2f(u16 x){
  union { unsigned u; float f; } v; v.u = ((unsigned)x) << 16; return v.f;
}
__device__ __forceinline__ u16 f2bf(float f){
  union { float f; unsigned u; } v; v.f = f;
  unsigned u = v.u;
  return (u16)((u + 0x7FFFu + ((u >> 16) & 1u)) >> 16);
}
union pk2 { unsigned u; _Float16 h[2]; };
__device__ __forceinline__ unsigned packh(float a, float b){
  pk2 p; p.h[0] = (_Float16)a; p.h[1] = (_Float16)b; return p.u;
}

// ---------------------------------------------------------------------------
// setup_kernel (1 block): BwT[g][k] bf16 (stride 136, rows 8..15 + cols 128..135
// zeroed) and cinit[8] into workspace.  Bw = [cpe_w2 ; -Wq] @ we_w1.
// ---------------------------------------------------------------------------
__global__ __launch_bounds__(256) void setup_kernel(
    const float* __restrict__ Wq, const float* __restrict__ bq,
    const float* __restrict__ cpe_w2, const float* __restrict__ cpe_b2,
    const float* __restrict__ we_w1,
    u16* __restrict__ bw, float* __restrict__ cinit)
{
  __shared__ float sWe[512];
  int tid = threadIdx.x;
  for (int e = tid; e < 512; e += 256) sWe[e] = we_w1[e];
  __syncthreads();
  int k = tid >> 1, g0 = (tid & 1)*4;
  const float* brow = (k < 64) ? (cpe_w2 + k*64) : (Wq + (k-64)*64);
  float sgn = (k < 64) ? 1.f : -1.f;
  float aw[4] = {0.f,0.f,0.f,0.f};
  for (int o = 0; o < 64; o++){
    float bo = brow[o]*sgn;
    #pragma unroll
    for (int gg=0; gg<4; gg++) aw[gg] += bo * sWe[o*8 + g0+gg];
  }
  #pragma unroll
  for (int gg=0; gg<4; gg++) bw[(g0+gg)*136 + k] = f2bf(aw[gg]);
  for (int e = tid; e < 2176; e += 256){
    int r = e / 136, cc = e % 136;
    if (r >= 8 || cc >= 128) bw[e] = 0;
  }
  if (tid < 8){
    float s = 0.f;
    for (int o = 0; o < 64; o++) s += (cpe_b2[o] - bq[o]) * sWe[o*8 + tid];
    cinit[tid] = s;
  }
}

// ---------------------------------------------------------------------------
// kv_kernel: xk|xv = fea^T @ [Wk|Wv] + [bk|bv] (bf16).  64 points/block, 1024 blocks.
// fea tile loaded coalesced (float4) -> LDS transpose -> ds_read_b128 A-frags.
// MFMA 16x16x32 bf16: A[m=l&15][k=(l>>4)*8+j], B[k][n=l&15], C/D row=(l>>4)*4+r, col=l&15.
// ---------------------------------------------------------------------------
__global__ __launch_bounds__(256) void kv_kernel(
    const float* __restrict__ fea,
    const float* __restrict__ Wk, const float* __restrict__ bk,
    const float* __restrict__ Wv, const float* __restrict__ bv,
    u16* __restrict__ xk, u16* __restrict__ xv)
{
  __shared__ u16 sWT[128*72];     // [col 0..127][k], bf16
  __shared__ u16 sA[64*72];       // fea tile [n][k]
  __shared__ u16 sOut[64*136];    // epilogue [pt][col]
  __shared__ float sBias[128];
  int tid = threadIdx.x;
  int l = tid & 63, w = tid >> 6, c = l & 15, q = l >> 4;
  int P0 = blockIdx.x * 64; int b = P0 >> 14; int n0 = P0 & (N_-1);
  const float* fb = fea + (long)b*C_*N_;

  // stage fea tile, coalesced
  #pragma unroll
  for (int pp = 0; pp < 4; pp++){
    int k = pp*16 + (tid >> 4);
    int nf = (tid & 15)*4;
    f32x4 v = *(const f32x4*)&fb[(long)k*N_ + n0 + nf];
    sA[(nf+0)*72+k] = f2bf(v[0]); sA[(nf+1)*72+k] = f2bf(v[1]);
    sA[(nf+2)*72+k] = f2bf(v[2]); sA[(nf+3)*72+k] = f2bf(v[3]);
  }
  // stage weights
  for (int e = tid; e < 8192; e += 256){
    int k = e >> 7, col = e & 127;
    float v = (col < 64) ? Wk[k*64 + col] : Wv[k*64 + (col-64)];
    sWT[col*72 + k] = f2bf(v);
  }
  if (tid < 128) sBias[tid] = (tid < 64) ? bk[tid] : bv[tid-64];
  __syncthreads();

  bf8v af0 = *(const bf8v*)&sA[(w*16+c)*72 + q*8];
  bf8v af1 = *(const bf8v*)&sA[(w*16+c)*72 + 32 + q*8];

  f32x4 acc[8];
  #pragma unroll
  for (int t = 0; t < 8; t++){
    float bias = sBias[16*t + c];
    f32x4 a_ = {bias, bias, bias, bias};
    bf8v b0 = *(const bf8v*)&sWT[(16*t + c)*72 + q*8];
    bf8v b1 = *(const bf8v*)&sWT[(16*t + c)*72 + 32 + q*8];
    a_ = __builtin_amdgcn_mfma_f32_16x16x32_bf16(af0, b0, a_, 0,0,0);
    a_ = __builtin_amdgcn_mfma_f32_16x16x32_bf16(af1, b1, a_, 0,0,0);
    acc[t] = a_;
  }
  #pragma unroll
  for (int t = 0; t < 8; t++)
    #pragma unroll
    for (int r = 0; r < 4; r++)
      sOut[(w*16 + q*4 + r)*136 + 16*t + c] = f2bf(acc[t][r]);
  __syncthreads();

  #pragma unroll
  for (int rep = 0; rep < 4; rep++){
    int chunk = rep*256 + tid;
    int pt = chunk >> 4, c8i = chunk & 15;
    uint4v val = *(const uint4v*)&sOut[pt*136 + c8i*8];
    int col8 = c8i*8;
    long row = (long)P0 + pt;
    if (col8 < 64) *(uint4v*)(xk + row*64 + col8)      = val;
    else           *(uint4v*)(xv + row*64 + (col8-64)) = val;
  }
}

// ---------------------------------------------------------------------------
// qc_kernel: qw[m,:8] = [relu(cp@w1f+pb) | cf] @ Bw + cinit.  64 pts/block, 1024 blocks.
// ---------------------------------------------------------------------------
__global__ __launch_bounds__(256) void qc_kernel(
    const float* __restrict__ center_pos, const float* __restrict__ center_fea,
    const float* __restrict__ cpe_w1, const float* __restrict__ cpe_s, const float* __restrict__ cpe_b,
    const u16* __restrict__ bw, const float* __restrict__ cinit,
    float* __restrict__ qw)
{
  __shared__ u16 sBw[16*136];
  __shared__ u16 sA[64*72];
  __shared__ float sW1[256];   // w1f 192 | pb 64
  __shared__ float sQ[512];
  int tid = threadIdx.x;
  int l = tid & 63, w = tid >> 6, c = l & 15, q = l >> 4;
  int P0 = blockIdx.x * 64; int b = P0 >> 14; int m0 = P0 & (M_-1);
  const float* cfb = center_fea + (long)b*C_*M_;

  #pragma unroll
  for (int pp = 0; pp < 4; pp++){
    int k = pp*16 + (tid >> 4);
    int nf = (tid & 15)*4;
    f32x4 v = *(const f32x4*)&cfb[(long)k*M_ + m0 + nf];
    sA[(nf+0)*72+k] = f2bf(v[0]); sA[(nf+1)*72+k] = f2bf(v[1]);
    sA[(nf+2)*72+k] = f2bf(v[2]); sA[(nf+3)*72+k] = f2bf(v[3]);
  }
  for (int e = tid; e < 2176; e += 256) sBw[e] = bw[e];
  if (tid < 64){
    float sc = cpe_s[tid];
    sW1[tid]     = cpe_w1[tid]*sc;
    sW1[64+tid]  = cpe_w1[64+tid]*sc;
    sW1[128+tid] = cpe_w1[128+tid]*sc;
    sW1[192+tid] = cpe_b[tid];
  }
  long c3 = (long)(P0 + w*16 + c)*3;
  float cp0 = center_pos[c3], cp1 = center_pos[c3+1], cp2 = center_pos[c3+2];
  __syncthreads();

  bf8v ah[2], acf[2];
  #pragma unroll
  for (int ks = 0; ks < 2; ks++){
    union { bf8v v; u16 sv[8]; } ua;
    #pragma unroll
    for (int j = 0; j < 8; j++){
      int h = ks*32 + q*8 + j;
      float hv = cp0*sW1[h] + cp1*sW1[64+h] + cp2*sW1[128+h] + sW1[192+h];
      ua.sv[j] = f2bf(fmaxf(hv, 0.f));
    }
    ah[ks] = ua.v;
  }
  acf[0] = *(const bf8v*)&sA[(w*16+c)*72 + q*8];
  acf[1] = *(const bf8v*)&sA[(w*16+c)*72 + 32 + q*8];

  float ci = (c < 8) ? cinit[c] : 0.f;
  f32x4 aq = {ci, ci, ci, ci};
  {
    bf8v b0 = *(const bf8v*)&sBw[c*136 + q*8];
    bf8v b1 = *(const bf8v*)&sBw[c*136 + 32 + q*8];
    bf8v b2 = *(const bf8v*)&sBw[c*136 + 64 + q*8];
    bf8v b3 = *(const bf8v*)&sBw[c*136 + 96 + q*8];
    aq = __builtin_amdgcn_mfma_f32_16x16x32_bf16(ah[0],  b0, aq, 0,0,0);
    aq = __builtin_amdgcn_mfma_f32_16x16x32_bf16(ah[1],  b1, aq, 0,0,0);
    aq = __builtin_amdgcn_mfma_f32_16x16x32_bf16(acf[0], b2, aq, 0,0,0);
    aq = __builtin_amdgcn_mfma_f32_16x16x32_bf16(acf[1], b3, aq, 0,0,0);
  }
  if (c < 8){
    #pragma unroll
    for (int r = 0; r < 4; r++) sQ[(w*16 + q*4 + r)*8 + c] = aq[r];
  }
  __syncthreads();
  for (int e = tid; e < 512; e += 256)
    qw[(long)P0*8 + e] = sQ[e];
}

// ---------------------------------------------------------------------------
// attn_kernel: 2 points per wave per iteration (4 iters), interleaved chains.
// ---------------------------------------------------------------------------
__global__ __launch_bounds__(256, 3) void attn_kernel(
    const float* __restrict__ center_pos, const float* __restrict__ pos,
    const int* __restrict__ idx,
    const float* __restrict__ pe_w1, const float* __restrict__ pe_s, const float* __restrict__ pe_b,
    const float* __restrict__ pe_w2, const float* __restrict__ pe_b2,
    const float* __restrict__ we_w1, const float* __restrict__ we_s, const float* __restrict__ we_b,
    const float* __restrict__ we_w2, const float* __restrict__ we_b2,
    const u16* __restrict__ xk, const u16* __restrict__ xv, const float* __restrict__ qw,
    float* __restrict__ out)
{
  int tid = threadIdx.x;
  __shared__ float s_w1f[192], s_pb[64], s_pb2[64], s_ww2[64];
  __shared__ float s_ws8[8], s_wb8[8], s_wb28[8];
  __shared__ u16  s_stage[64*72 + 16*72];  // pe_w2^T | we_w1^T (zero-padded)
  __shared__ u16  s_vt[4*2*16*72];         // per-wave 2 V tiles
  __shared__ float s_tile[32*66];

  if (tid < 64){
    float sc = pe_s[tid];
    s_w1f[tid]     = pe_w1[tid]*sc;
    s_w1f[64+tid]  = pe_w1[64+tid]*sc;
    s_w1f[128+tid] = pe_w1[128+tid]*sc;
    s_pb[tid]  = pe_b[tid];
    s_pb2[tid] = pe_b2[tid];
    s_ww2[tid] = we_w2[tid];
  }
  if (tid >= 64 && tid < 72){
    int g = tid-64;
    s_ws8[g]=we_s[g]; s_wb8[g]=we_b[g]; s_wb28[g]=we_b2[g];
  }
  // stage pe_w2 transposed: [col o][row k], stride 72
  #pragma unroll
  for (int pp = 0; pp < 4; pp++){
    int row = pp*16 + (tid >> 4);
    int colf = (tid & 15)*4;
    f32x4 v = *(const f32x4*)&pe_w2[row*64 + colf];
    s_stage[(colf+0)*72+row] = f2bf(v[0]); s_stage[(colf+1)*72+row] = f2bf(v[1]);
    s_stage[(colf+2)*72+row] = f2bf(v[2]); s_stage[(colf+3)*72+row] = f2bf(v[3]);
  }
  // stage we_w1 transposed: rows c=0..7 valid, 8..15 zero
  u16* s2 = s_stage + 64*72;
  for (int e = tid; e < 512; e += 256){
    int k = e >> 3, cc = e & 7;
    s2[cc*72 + k] = f2bf(we_w1[e]);
  }
  for (int e = tid; e < 576; e += 256) s2[576 + e] = 0;
  __syncthreads();

  int w = tid >> 6, l = tid & 63, c = l & 15, q = l >> 4, c8 = c & 7, qb = l & 48;

  bf8v pw2f[4][2], ww1f[2];
  #pragma unroll
  for (int t = 0; t < 4; t++){
    pw2f[t][0] = *(const bf8v*)&s_stage[(t*16+c)*72 + q*8];
    pw2f[t][1] = *(const bf8v*)&s_stage[(t*16+c)*72 + 32 + q*8];
  }
  ww1f[0] = *(const bf8v*)&s2[c*72 + q*8];
  ww1f[1] = *(const bf8v*)&s2[c*72 + 32 + q*8];

  float ws_c = s_ws8[c8], wb_c = s_wb8[c8], wb2_c = s_wb28[c8];
  float w2col[8];
  #pragma unroll
  for (int g = 0; g < 8; g++) w2col[g] = s_ww2[g*8 + c8];
  float pb2t[4];
  #pragma unroll
  for (int t = 0; t < 4; t++) pb2t[t] = s_pb2[t*16 + c];

  int pbase = blockIdx.x * 32;
  int b = pbase >> 14;
  long xkb = (long)b * N_ * 64;
  u16* vt0 = s_vt + w*(2*16*72);
  u16* vt1 = vt0 + 16*72;
  int ch = c >> 3;

  // preload scalars for pair 0
  int pb0 = pbase + w*8;
  int iv0 = idx[(long)pb0*16 + c];
  int iv1 = idx[(long)(pb0+1)*16 + c];
  float qp0 = qw[(long)pb0*8 + c8];
  float qp1 = qw[(long)(pb0+1)*8 + c8];
  long c30 = (long)pb0*3, c31 = (long)(pb0+1)*3;
  float cpA0 = center_pos[c30], cpA1 = center_pos[c30+1], cpA2 = center_pos[c30+2];
  float cpB0 = center_pos[c31], cpB1 = center_pos[c31+1], cpB2 = center_pos[c31+2];

  #pragma unroll 1
  for (int i = 0; i < 4; i++){
    // ---- issue gathers for both points ----
    long prA = ((long)b*N_ + iv0)*3, prB = ((long)b*N_ + iv1)*3;
    float pxA = pos[prA], pyA = pos[prA+1], pzA = pos[prA+2];
    float pxB = pos[prB], pyB = pos[prB+1], pzB = pos[prB+2];
    const u16* kr0 = xk + xkb + (long)iv0*64;
    const u16* kr1 = xk + xkb + (long)iv1*64;
    bf8v ka00 = *(const bf8v*)(kr0 + q*8),  ka01 = *(const bf8v*)(kr0 + 32 + q*8);
    bf8v ka10 = *(const bf8v*)(kr1 + q*8),  ka11 = *(const bf8v*)(kr1 + 32 + q*8);
    const u16* vr0 = xv + xkb + (long)iv0*64;
    const u16* vr1 = xv + xkb + (long)iv1*64;
    uint4v va00 = *(const uint4v*)(vr0 + q*8), va01 = *(const uint4v*)(vr0 + 32 + q*8);
    uint4v va10 = *(const uint4v*)(vr1 + q*8), va11 = *(const uint4v*)(vr1 + 32 + q*8);

    // ---- prefetch next pair scalars ----
    int p2 = pb0 + ((i < 3) ? 2*i + 2 : 2*i);
    int p3 = p2 + 1;
    int ivn0 = idx[(long)p2*16 + c];
    int ivn1 = idx[(long)p3*16 + c];
    float qpn0 = qw[(long)p2*8 + c8];
    float qpn1 = qw[(long)p3*8 + c8];
    long c3n0 = (long)p2*3, c3n1 = (long)p3*3;
    float cpnA0 = center_pos[c3n0], cpnA1 = center_pos[c3n0+1], cpnA2 = center_pos[c3n0+2];
    float cpnB0 = center_pos[c3n1], cpnB1 = center_pos[c3n1+1], cpnB2 = center_pos[c3n1+2];

    // ---- stash V tiles ----
    *(uint4v*)&vt0[c*72 + q*8]      = va00;
    *(uint4v*)&vt0[c*72 + 32 + q*8] = va01;
    *(uint4v*)&vt1[c*72 + q*8]      = va10;
    *(uint4v*)&vt1[c*72 + 32 + q*8] = va11;

    // ---- H1 fragments for both ----
    float npA0 = pxA - cpA0, npA1 = pyA - cpA1, npA2 = pzA - cpA2;
    float npB0 = pxB - cpB0, npB1 = pyB - cpB1, npB2 = pzB - cpB2;
    bf8v h1A[2], h1B[2];
    #pragma unroll
    for (int ks = 0; ks < 2; ks++){
      union { bf8v v; u16 s[8]; } ha, hb;
      #pragma unroll
      for (int j = 0; j < 8; j++){
        int o = ks*32 + q*8 + j;
        float w1 = s_w1f[o], w2 = s_w1f[64+o], w3 = s_w1f[128+o], bb = s_pb[o];
        ha.s[j] = f2bf(fmaxf(npA0*w1 + npA1*w2 + npA2*w3 + bb, 0.f));
        hb.s[j] = f2bf(fmaxf(npB0*w1 + npB1*w2 + npB2*w3 + bb, 0.f));
      }
      h1A[ks] = ha.v; h1B[ks] = hb.v;
    }

    // ---- weight-MLP hidden via MFMA (both points) ----
    f32x4 h2a0 = {qp0, qp0, qp0, qp0};
    f32x4 h2a1 = {qp1, qp1, qp1, qp1};
    h2a0 = __builtin_amdgcn_mfma_f32_16x16x32_bf16(ka00, ww1f[0], h2a0, 0,0,0);
    h2a1 = __builtin_amdgcn_mfma_f32_16x16x32_bf16(ka10, ww1f[0], h2a1, 0,0,0);
    h2a0 = __builtin_amdgcn_mfma_f32_16x16x32_bf16(ka01, ww1f[1], h2a0, 0,0,0);
    h2a1 = __builtin_amdgcn_mfma_f32_16x16x32_bf16(ka11, ww1f[1], h2a1, 0,0,0);

    // ---- softmax weights (both points, interleaved) ----
    float h2r0[4], h2r1[4];
    #pragma unroll
    for (int r = 0; r < 4; r++){
      h2r0[r] = fmaxf(h2a0[r]*ws_c + wb_c, 0.f);
      h2r1[r] = fmaxf(h2a1[r]*ws_c + wb_c, 0.f);
    }
    unsigned hp00 = packh(h2r0[0], h2r0[1]), hp01 = packh(h2r0[2], h2r0[3]);
    unsigned hp10 = packh(h2r1[0], h2r1[1]), hp11 = packh(h2r1[2], h2r1[3]);
    float wl0[4] = {wb2_c, wb2_c, wb2_c, wb2_c};
    float wl1[4] = {wb2_c, wb2_c, wb2_c, wb2_c};
    #pragma unroll
    for (int g = 0; g < 8; g++){
      float wg = w2col[g];
      pk2 a0; a0.u = (unsigned)__shfl((int)hp00, qb | g, 64);
      pk2 a1; a1.u = (unsigned)__shfl((int)hp01, qb | g, 64);
      pk2 b0; b0.u = (unsigned)__shfl((int)hp10, qb | g, 64);
      pk2 b1; b1.u = (unsigned)__shfl((int)hp11, qb | g, 64);
      wl0[0] += (float)a0.h[0]*wg; wl0[1] += (float)a0.h[1]*wg;
      wl0[2] += (float)a1.h[0]*wg; wl0[3] += (float)a1.h[1]*wg;
      wl1[0] += (float)b0.h[0]*wg; wl1[1] += (float)b0.h[1]*wg;
      wl1[2] += (float)b1.h[0]*wg; wl1[3] += (float)b1.h[1]*wg;
    }
    float e0[4], e1[4];
    #pragma unroll
    for (int r = 0; r < 4; r++){
      e0[r] = exp2f(wl0[r]*1.44269504f);
      e1[r] = exp2f(wl1[r]*1.44269504f);
    }
    float sm0 = e0[0]+e0[1]+e0[2]+e0[3];
    float sm1 = e1[0]+e1[1]+e1[2]+e1[3];
    sm0 += __shfl_xor(sm0, 16, 64); sm1 += __shfl_xor(sm1, 16, 64);
    sm0 += __shfl_xor(sm0, 32, 64); sm1 += __shfl_xor(sm1, 32, 64);
    float rn0 = 1.0f/sm0, rn1 = 1.0f/sm1;
    #pragma unroll
    for (int r = 0; r < 4; r++){ e0[r] *= rn0; e1[r] *= rn1; }
    unsigned ep00 = packh(e0[0], e0[1]), ep01 = packh(e0[2], e0[3]);
    unsigned ep10 = packh(e1[0], e1[1]), ep11 = packh(e1[2], e1[3]);

    // ---- PR MFMA fused with weighted-V output, per t ----
    float ov0[4], ov1[4];
    #pragma unroll
    for (int t = 0; t < 4; t++){
      f32x4 z0 = {0.f,0.f,0.f,0.f}, z1 = {0.f,0.f,0.f,0.f};
      z0 = __builtin_amdgcn_mfma_f32_16x16x32_bf16(h1A[0], pw2f[t][0], z0, 0,0,0);
      z1 = __builtin_amdgcn_mfma_f32_16x16x32_bf16(h1B[0], pw2f[t][0], z1, 0,0,0);
      z0 = __builtin_amdgcn_mfma_f32_16x16x32_bf16(h1A[1], pw2f[t][1], z0, 0,0,0);
      z1 = __builtin_amdgcn_mfma_f32_16x16x32_bf16(h1B[1], pw2f[t][1], z1, 0,0,0);
      int src = qb | (t*2 + ch);
      pk2 wA0; wA0.u = (unsigned)__shfl((int)ep00, src, 64);
      pk2 wA1; wA1.u = (unsigned)__shfl((int)ep01, src, 64);
      pk2 wB0; wB0.u = (unsigned)__shfl((int)ep10, src, 64);
      pk2 wB1; wB1.u = (unsigned)__shfl((int)ep11, src, 64);
      float a = 0.f, bacc = 0.f;
      a += (z0[0] + bf2f(vt0[(q*4+0)*72 + t*16 + c])) * (float)wA0.h[0];
      a += (z0[1] + bf2f(vt0[(q*4+1)*72 + t*16 + c])) * (float)wA0.h[1];
      a += (z0[2] + bf2f(vt0[(q*4+2)*72 + t*16 + c])) * (float)wA1.h[0];
      a += (z0[3] + bf2f(vt0[(q*4+3)*72 + t*16 + c])) * (float)wA1.h[1];
      bacc += (z1[0] + bf2f(vt1[(q*4+0)*72 + t*16 + c])) * (float)wB0.h[0];
      bacc += (z1[1] + bf2f(vt1[(q*4+1)*72 + t*16 + c])) * (float)wB0.h[1];
      bacc += (z1[2] + bf2f(vt1[(q*4+2)*72 + t*16 + c])) * (float)wB1.h[0];
      bacc += (z1[3] + bf2f(vt1[(q*4+3)*72 + t*16 + c])) * (float)wB1.h[1];
      ov0[t] = a; ov1[t] = bacc;
    }
    #pragma unroll
    for (int t = 0; t < 4; t++){
      ov0[t] += __shfl_xor(ov0[t], 16, 64);
      ov1[t] += __shfl_xor(ov1[t], 16, 64);
      ov0[t] += __shfl_xor(ov0[t], 32, 64);
      ov1[t] += __shfl_xor(ov1[t], 32, 64);
      ov0[t] += pb2t[t]; ov1[t] += pb2t[t];
    }
    float s0 = ov0[0], s1 = ov1[0];
    s0 = (q==1) ? ov0[1] : s0;  s1 = (q==1) ? ov1[1] : s1;
    s0 = (q==2) ? ov0[2] : s0;  s1 = (q==2) ? ov1[2] : s1;
    s0 = (q==3) ? ov0[3] : s0;  s1 = (q==3) ? ov1[3] : s1;
    s_tile[(w*8 + 2*i + 0)*66 + l] = s0;
    s_tile[(w*8 + 2*i + 1)*66 + l] = s1;

    // rotate
    iv0 = ivn0; iv1 = ivn1; qp0 = qpn0; qp1 = qpn1;
    cpA0 = cpnA0; cpA1 = cpnA1; cpA2 = cpnA2;
    cpB0 = cpnB0; cpB1 = cpnB1; cpB2 = cpnB2;
  }
  __syncthreads();

  int o0 = tid >> 5, pt = tid & 31;
  int m0 = pbase & (M_-1);
  long outb = ((long)b*64) * M_ + m0 + pt;
  #pragma unroll
  for (int ii = 0; ii < 8; ii++){
    int o = o0*8 + ii;
    out[outb + (long)o*M_] = s_tile[pt*66 + o];
  }
}

extern "C" void kernel_launch(void* const* d_in, const int* in_sizes, int n_in,
                              void* d_out, int out_size, void* d_ws, size_t ws_size,
                              hipStream_t stream) {
  const float* center_pos = (const float*)d_in[0];
  const float* center_fea = (const float*)d_in[1];
  const float* pos        = (const float*)d_in[2];
  const float* fea        = (const float*)d_in[3];
  const int*   idx        = (const int*)d_in[4];
  const float* Wq = (const float*)d_in[5];   const float* bq = (const float*)d_in[6];
  const float* Wk = (const float*)d_in[7];   const float* bk = (const float*)d_in[8];
  const float* Wv = (const float*)d_in[9];   const float* bv = (const float*)d_in[10];
  const float* cpe_w1 = (const float*)d_in[11]; const float* cpe_s = (const float*)d_in[12];
  const float* cpe_b  = (const float*)d_in[13]; const float* cpe_w2 = (const float*)d_in[14];
  const float* cpe_b2 = (const float*)d_in[15];
  const float* pe_w1 = (const float*)d_in[16]; const float* pe_s = (const float*)d_in[17];
  const float* pe_b  = (const float*)d_in[18]; const float* pe_w2 = (const float*)d_in[19];
  const float* pe_b2 = (const float*)d_in[20];
  const float* we_w1 = (const float*)d_in[21]; const float* we_s = (const float*)d_in[22];
  const float* we_b  = (const float*)d_in[23]; const float* we_w2 = (const float*)d_in[24];
  const float* we_b2 = (const float*)d_in[25];

  // ws: xk u16 | xv u16 | qw f32 | bw u16 | cinit f32
  const size_t SZ = (size_t)B_*N_*64;
  u16* xk = (u16*)d_ws;
  u16* xv = xk + SZ;
  float* qwp = (float*)(xv + SZ);
  u16* bwp = (u16*)(qwp + (size_t)B_*M_*8);
  float* cinitp = (float*)(bwp + 2176);
  float* outp = (float*)d_out;

  hipLaunchKernelGGL(setup_kernel, dim3(1), dim3(256), 0, stream,
      Wq, bq, cpe_w2, cpe_b2, we_w1, bwp, cinitp);
  hipLaunchKernelGGL(kv_kernel, dim3(1024), dim3(256), 0, stream,
      fea, Wk, bk, Wv, bv, xk, xv);
  hipLaunchKernelGGL(qc_kernel, dim3(1024), dim3(256), 0, stream,
      center_pos, center_fea, cpe_w1, cpe_s, cpe_b, bwp, cinitp, qwp);
  hipLaunchKernelGGL(attn_kernel, dim3(2048), dim3(256), 0, stream,
      center_pos, pos, idx, pe_w1, pe_s, pe_b, pe_w2, pe_b2,
      we_w1, we_s, we_b, we_w2, we_b2, xk, xv, qwp, outp);
}

// Round 6
// 224.705 us; speedup vs baseline: 1.3768x; 1.3768x over previous
//
#include <hip/hip_runtime.h>
#include <hip/hip_bf16.h>

typedef unsigned short u16;
typedef __attribute__((ext_vector_type(8))) __bf16 bf8v;
typedef __attribute__((ext_vector_type(4))) float f32x4;
typedef __attribute__((ext_vector_type(4))) unsigned uint4v;

#define B_ 4
#define N_ 16384
#define M_ 16384
#define K_ 16
#define C_ 64
#define O_ 64
#define G_ 8

__device__ __forceinline__ float bf2f(u16 x){
  union { unsigned u; float f; } v; v.u = ((unsigned)x) << 16; return v.f;
}
__device__ __forceinline__ u16 f2bf(float f){
  union { float f; unsigned u; } v; v.f = f;
  unsigned u = v.u;
  return (u16)((u + 0x7FFFu + ((u >> 16) & 1u)) >> 16);
}
union pk2 { unsigned u; _Float16 h[2]; };
__device__ __forceinline__ unsigned packh(float a, float b){
  pk2 p; p.h[0] = (_Float16)a; p.h[1] = (_Float16)b; return p.u;
}

// ---------------------------------------------------------------------------
// setup_kernel (1 block): BwT[g][k] bf16 (stride 136) and cinit[8].
// Bw = [cpe_w2 ; -Wq] @ we_w1.
// ---------------------------------------------------------------------------
__global__ __launch_bounds__(256) void setup_kernel(
    const float* __restrict__ Wq, const float* __restrict__ bq,
    const float* __restrict__ cpe_w2, const float* __restrict__ cpe_b2,
    const float* __restrict__ we_w1,
    u16* __restrict__ bw, float* __restrict__ cinit)
{
  __shared__ float sWe[512];
  int tid = threadIdx.x;
  for (int e = tid; e < 512; e += 256) sWe[e] = we_w1[e];
  __syncthreads();
  int k = tid >> 1, g0 = (tid & 1)*4;
  const float* brow = (k < 64) ? (cpe_w2 + k*64) : (Wq + (k-64)*64);
  float sgn = (k < 64) ? 1.f : -1.f;
  float aw[4] = {0.f,0.f,0.f,0.f};
  for (int o = 0; o < 64; o++){
    float bo = brow[o]*sgn;
    #pragma unroll
    for (int gg=0; gg<4; gg++) aw[gg] += bo * sWe[o*8 + g0+gg];
  }
  #pragma unroll
  for (int gg=0; gg<4; gg++) bw[(g0+gg)*136 + k] = f2bf(aw[gg]);
  for (int e = tid; e < 2176; e += 256){
    int r = e / 136, cc = e % 136;
    if (r >= 8 || cc >= 128) bw[e] = 0;
  }
  if (tid < 8){
    float s = 0.f;
    for (int o = 0; o < 64; o++) s += (cpe_b2[o] - bq[o]) * sWe[o*8 + tid];
    cinit[tid] = s;
  }
}

// ---------------------------------------------------------------------------
// pre_kernel (merged): blocks [0,1024) KV, [1024,2048) QC. 64 points/block.
// MFMA 16x16x32 bf16: A[m=l&15][k=(l>>4)*8+j], B[k][n=l&15],
//                     C/D row=(l>>4)*4+r, col=l&15.
// ---------------------------------------------------------------------------
__global__ __launch_bounds__(256) void pre_kernel(
    const float* __restrict__ center_pos, const float* __restrict__ center_fea,
    const float* __restrict__ fea,
    const float* __restrict__ Wk, const float* __restrict__ bk,
    const float* __restrict__ Wv, const float* __restrict__ bv,
    const float* __restrict__ cpe_w1, const float* __restrict__ cpe_s, const float* __restrict__ cpe_b,
    const u16* __restrict__ bw, const float* __restrict__ cinit,
    u16* __restrict__ xk, u16* __restrict__ xv, float* __restrict__ qw)
{
  __shared__ u16 sWT[128*72];     // KV: [col][k] ; QC: sBw 16*136 at base
  __shared__ u16 sA[64*72];       // staged A tile [n][k]
  __shared__ u16 sOut[64*136];    // KV epilogue ; QC: sQ f32 512 at base
  __shared__ float sMisc[256];
  int tid = threadIdx.x;
  int l = tid & 63, w = tid >> 6, c = l & 15, q = l >> 4;
  int blk = blockIdx.x;

  if (blk < 1024){
    // ================ KV ================
    int P0 = blk * 64; int b = P0 >> 14; int n0 = P0 & (N_-1);
    const float* fb = fea + (long)b*C_*N_;
    #pragma unroll
    for (int pp = 0; pp < 4; pp++){
      int k = pp*16 + (tid >> 4);
      int nf = (tid & 15)*4;
      f32x4 v = *(const f32x4*)&fb[(long)k*N_ + n0 + nf];
      sA[(nf+0)*72+k] = f2bf(v[0]); sA[(nf+1)*72+k] = f2bf(v[1]);
      sA[(nf+2)*72+k] = f2bf(v[2]); sA[(nf+3)*72+k] = f2bf(v[3]);
    }
    for (int e = tid; e < 8192; e += 256){
      int k = e >> 7, col = e & 127;
      float v = (col < 64) ? Wk[k*64 + col] : Wv[k*64 + (col-64)];
      sWT[col*72 + k] = f2bf(v);
    }
    if (tid < 128) sMisc[tid] = (tid < 64) ? bk[tid] : bv[tid-64];
    __syncthreads();

    bf8v af0 = *(const bf8v*)&sA[(w*16+c)*72 + q*8];
    bf8v af1 = *(const bf8v*)&sA[(w*16+c)*72 + 32 + q*8];

    f32x4 acc[8];
    #pragma unroll
    for (int t = 0; t < 8; t++){
      float bias = sMisc[16*t + c];
      f32x4 a_ = {bias, bias, bias, bias};
      bf8v b0 = *(const bf8v*)&sWT[(16*t + c)*72 + q*8];
      bf8v b1 = *(const bf8v*)&sWT[(16*t + c)*72 + 32 + q*8];
      a_ = __builtin_amdgcn_mfma_f32_16x16x32_bf16(af0, b0, a_, 0,0,0);
      a_ = __builtin_amdgcn_mfma_f32_16x16x32_bf16(af1, b1, a_, 0,0,0);
      acc[t] = a_;
    }
    #pragma unroll
    for (int t = 0; t < 8; t++)
      #pragma unroll
      for (int r = 0; r < 4; r++)
        sOut[(w*16 + q*4 + r)*136 + 16*t + c] = f2bf(acc[t][r]);
    __syncthreads();

    #pragma unroll
    for (int rep = 0; rep < 4; rep++){
      int chunk = rep*256 + tid;
      int pt = chunk >> 4, c8i = chunk & 15;
      uint4v val = *(const uint4v*)&sOut[pt*136 + c8i*8];
      int col8 = c8i*8;
      long row = (long)P0 + pt;
      if (col8 < 64) *(uint4v*)(xk + row*64 + col8)      = val;
      else           *(uint4v*)(xv + row*64 + (col8-64)) = val;
    }
  } else {
    // ================ QC ================
    int P0 = (blk - 1024) * 64; int b = P0 >> 14; int m0 = P0 & (M_-1);
    const float* cfb = center_fea + (long)b*C_*M_;
    float* sQ = (float*)sOut;
    #pragma unroll
    for (int pp = 0; pp < 4; pp++){
      int k = pp*16 + (tid >> 4);
      int nf = (tid & 15)*4;
      f32x4 v = *(const f32x4*)&cfb[(long)k*M_ + m0 + nf];
      sA[(nf+0)*72+k] = f2bf(v[0]); sA[(nf+1)*72+k] = f2bf(v[1]);
      sA[(nf+2)*72+k] = f2bf(v[2]); sA[(nf+3)*72+k] = f2bf(v[3]);
    }
    for (int e = tid; e < 2176; e += 256) sWT[e] = bw[e];
    if (tid < 64){
      float sc = cpe_s[tid];
      sMisc[tid]     = cpe_w1[tid]*sc;
      sMisc[64+tid]  = cpe_w1[64+tid]*sc;
      sMisc[128+tid] = cpe_w1[128+tid]*sc;
      sMisc[192+tid] = cpe_b[tid];
    }
    long c3 = (long)(P0 + w*16 + c)*3;
    float cp0 = center_pos[c3], cp1 = center_pos[c3+1], cp2 = center_pos[c3+2];
    __syncthreads();

    bf8v ah[2];
    #pragma unroll
    for (int ks = 0; ks < 2; ks++){
      union { bf8v v; u16 sv[8]; } ua;
      #pragma unroll
      for (int j = 0; j < 8; j++){
        int h = ks*32 + q*8 + j;
        float hv = cp0*sMisc[h] + cp1*sMisc[64+h] + cp2*sMisc[128+h] + sMisc[192+h];
        ua.sv[j] = f2bf(fmaxf(hv, 0.f));
      }
      ah[ks] = ua.v;
    }
    bf8v acf0 = *(const bf8v*)&sA[(w*16+c)*72 + q*8];
    bf8v acf1 = *(const bf8v*)&sA[(w*16+c)*72 + 32 + q*8];

    float ci = (c < 8) ? cinit[c] : 0.f;
    f32x4 aq = {ci, ci, ci, ci};
    {
      bf8v b0 = *(const bf8v*)&sWT[c*136 + q*8];
      bf8v b1 = *(const bf8v*)&sWT[c*136 + 32 + q*8];
      bf8v b2 = *(const bf8v*)&sWT[c*136 + 64 + q*8];
      bf8v b3 = *(const bf8v*)&sWT[c*136 + 96 + q*8];
      aq = __builtin_amdgcn_mfma_f32_16x16x32_bf16(ah[0], b0, aq, 0,0,0);
      aq = __builtin_amdgcn_mfma_f32_16x16x32_bf16(ah[1], b1, aq, 0,0,0);
      aq = __builtin_amdgcn_mfma_f32_16x16x32_bf16(acf0,  b2, aq, 0,0,0);
      aq = __builtin_amdgcn_mfma_f32_16x16x32_bf16(acf1,  b3, aq, 0,0,0);
    }
    __syncthreads();
    if (c < 8){
      #pragma unroll
      for (int r = 0; r < 4; r++) sQ[(w*16 + q*4 + r)*8 + c] = aq[r];
    }
    __syncthreads();
    for (int e = tid; e < 512; e += 256)
      qw[(long)P0*8 + e] = sQ[e];
  }
}

// ---------------------------------------------------------------------------
// attn_kernel: 2 points per wave per iteration (4 iters), interleaved chains.
// Identical to round-5 version EXCEPT no min-waves cap (no spills).
// ---------------------------------------------------------------------------
__global__ __launch_bounds__(256) void attn_kernel(
    const float* __restrict__ center_pos, const float* __restrict__ pos,
    const int* __restrict__ idx,
    const float* __restrict__ pe_w1, const float* __restrict__ pe_s, const float* __restrict__ pe_b,
    const float* __restrict__ pe_w2, const float* __restrict__ pe_b2,
    const float* __restrict__ we_w1, const float* __restrict__ we_s, const float* __restrict__ we_b,
    const float* __restrict__ we_w2, const float* __restrict__ we_b2,
    const u16* __restrict__ xk, const u16* __restrict__ xv, const float* __restrict__ qw,
    float* __restrict__ out)
{
  int tid = threadIdx.x;
  __shared__ float s_w1f[192], s_pb[64], s_pb2[64], s_ww2[64];
  __shared__ float s_ws8[8], s_wb8[8], s_wb28[8];
  __shared__ u16  s_stage[64*72 + 16*72];  // pe_w2^T | we_w1^T (zero-padded)
  __shared__ u16  s_vt[4*2*16*72];         // per-wave 2 V tiles
  __shared__ float s_tile[32*66];

  if (tid < 64){
    float sc = pe_s[tid];
    s_w1f[tid]     = pe_w1[tid]*sc;
    s_w1f[64+tid]  = pe_w1[64+tid]*sc;
    s_w1f[128+tid] = pe_w1[128+tid]*sc;
    s_pb[tid]  = pe_b[tid];
    s_pb2[tid] = pe_b2[tid];
    s_ww2[tid] = we_w2[tid];
  }
  if (tid >= 64 && tid < 72){
    int g = tid-64;
    s_ws8[g]=we_s[g]; s_wb8[g]=we_b[g]; s_wb28[g]=we_b2[g];
  }
  #pragma unroll
  for (int pp = 0; pp < 4; pp++){
    int row = pp*16 + (tid >> 4);
    int colf = (tid & 15)*4;
    f32x4 v = *(const f32x4*)&pe_w2[row*64 + colf];
    s_stage[(colf+0)*72+row] = f2bf(v[0]); s_stage[(colf+1)*72+row] = f2bf(v[1]);
    s_stage[(colf+2)*72+row] = f2bf(v[2]); s_stage[(colf+3)*72+row] = f2bf(v[3]);
  }
  u16* s2 = s_stage + 64*72;
  for (int e = tid; e < 512; e += 256){
    int k = e >> 3, cc = e & 7;
    s2[cc*72 + k] = f2bf(we_w1[e]);
  }
  for (int e = tid; e < 576; e += 256) s2[576 + e] = 0;
  __syncthreads();

  int w = tid >> 6, l = tid & 63, c = l & 15, q = l >> 4, c8 = c & 7, qb = l & 48;

  bf8v pw2f[4][2], ww1f[2];
  #pragma unroll
  for (int t = 0; t < 4; t++){
    pw2f[t][0] = *(const bf8v*)&s_stage[(t*16+c)*72 + q*8];
    pw2f[t][1] = *(const bf8v*)&s_stage[(t*16+c)*72 + 32 + q*8];
  }
  ww1f[0] = *(const bf8v*)&s2[c*72 + q*8];
  ww1f[1] = *(const bf8v*)&s2[c*72 + 32 + q*8];

  float ws_c = s_ws8[c8], wb_c = s_wb8[c8], wb2_c = s_wb28[c8];
  float w2col[8];
  #pragma unroll
  for (int g = 0; g < 8; g++) w2col[g] = s_ww2[g*8 + c8];
  float pb2t[4];
  #pragma unroll
  for (int t = 0; t < 4; t++) pb2t[t] = s_pb2[t*16 + c];

  int pbase = blockIdx.x * 32;
  int b = pbase >> 14;
  long xkb = (long)b * N_ * 64;
  u16* vt0 = s_vt + w*(2*16*72);
  u16* vt1 = vt0 + 16*72;
  int ch = c >> 3;

  int pb0 = pbase + w*8;
  int iv0 = idx[(long)pb0*16 + c];
  int iv1 = idx[(long)(pb0+1)*16 + c];
  float qp0 = qw[(long)pb0*8 + c8];
  float qp1 = qw[(long)(pb0+1)*8 + c8];
  long c30 = (long)pb0*3, c31 = (long)(pb0+1)*3;
  float cpA0 = center_pos[c30], cpA1 = center_pos[c30+1], cpA2 = center_pos[c30+2];
  float cpB0 = center_pos[c31], cpB1 = center_pos[c31+1], cpB2 = center_pos[c31+2];

  #pragma unroll 1
  for (int i = 0; i < 4; i++){
    long prA = ((long)b*N_ + iv0)*3, prB = ((long)b*N_ + iv1)*3;
    float pxA = pos[prA], pyA = pos[prA+1], pzA = pos[prA+2];
    float pxB = pos[prB], pyB = pos[prB+1], pzB = pos[prB+2];
    const u16* kr0 = xk + xkb + (long)iv0*64;
    const u16* kr1 = xk + xkb + (long)iv1*64;
    bf8v ka00 = *(const bf8v*)(kr0 + q*8),  ka01 = *(const bf8v*)(kr0 + 32 + q*8);
    bf8v ka10 = *(const bf8v*)(kr1 + q*8),  ka11 = *(const bf8v*)(kr1 + 32 + q*8);
    const u16* vr0 = xv + xkb + (long)iv0*64;
    const u16* vr1 = xv + xkb + (long)iv1*64;
    uint4v va00 = *(const uint4v*)(vr0 + q*8), va01 = *(const uint4v*)(vr0 + 32 + q*8);
    uint4v va10 = *(const uint4v*)(vr1 + q*8), va11 = *(const uint4v*)(vr1 + 32 + q*8);

    int p2 = pb0 + ((i < 3) ? 2*i + 2 : 2*i);
    int p3 = p2 + 1;
    int ivn0 = idx[(long)p2*16 + c];
    int ivn1 = idx[(long)p3*16 + c];
    float qpn0 = qw[(long)p2*8 + c8];
    float qpn1 = qw[(long)p3*8 + c8];
    long c3n0 = (long)p2*3, c3n1 = (long)p3*3;
    float cpnA0 = center_pos[c3n0], cpnA1 = center_pos[c3n0+1], cpnA2 = center_pos[c3n0+2];
    float cpnB0 = center_pos[c3n1], cpnB1 = center_pos[c3n1+1], cpnB2 = center_pos[c3n1+2];

    *(uint4v*)&vt0[c*72 + q*8]      = va00;
    *(uint4v*)&vt0[c*72 + 32 + q*8] = va01;
    *(uint4v*)&vt1[c*72 + q*8]      = va10;
    *(uint4v*)&vt1[c*72 + 32 + q*8] = va11;

    float npA0 = pxA - cpA0, npA1 = pyA - cpA1, npA2 = pzA - cpA2;
    float npB0 = pxB - cpB0, npB1 = pyB - cpB1, npB2 = pzB - cpB2;
    bf8v h1A[2], h1B[2];
    #pragma unroll
    for (int ks = 0; ks < 2; ks++){
      union { bf8v v; u16 s[8]; } ha, hb;
      #pragma unroll
      for (int j = 0; j < 8; j++){
        int o = ks*32 + q*8 + j;
        float w1 = s_w1f[o], w2 = s_w1f[64+o], w3 = s_w1f[128+o], bb = s_pb[o];
        ha.s[j] = f2bf(fmaxf(npA0*w1 + npA1*w2 + npA2*w3 + bb, 0.f));
        hb.s[j] = f2bf(fmaxf(npB0*w1 + npB1*w2 + npB2*w3 + bb, 0.f));
      }
      h1A[ks] = ha.v; h1B[ks] = hb.v;
    }

    f32x4 h2a0 = {qp0, qp0, qp0, qp0};
    f32x4 h2a1 = {qp1, qp1, qp1, qp1};
    h2a0 = __builtin_amdgcn_mfma_f32_16x16x32_bf16(ka00, ww1f[0], h2a0, 0,0,0);
    h2a1 = __builtin_amdgcn_mfma_f32_16x16x32_bf16(ka10, ww1f[0], h2a1, 0,0,0);
    h2a0 = __builtin_amdgcn_mfma_f32_16x16x32_bf16(ka01, ww1f[1], h2a0, 0,0,0);
    h2a1 = __builtin_amdgcn_mfma_f32_16x16x32_bf16(ka11, ww1f[1], h2a1, 0,0,0);

    float h2r0[4], h2r1[4];
    #pragma unroll
    for (int r = 0; r < 4; r++){
      h2r0[r] = fmaxf(h2a0[r]*ws_c + wb_c, 0.f);
      h2r1[r] = fmaxf(h2a1[r]*ws_c + wb_c, 0.f);
    }
    unsigned hp00 = packh(h2r0[0], h2r0[1]), hp01 = packh(h2r0[2], h2r0[3]);
    unsigned hp10 = packh(h2r1[0], h2r1[1]), hp11 = packh(h2r1[2], h2r1[3]);
    float wl0[4] = {wb2_c, wb2_c, wb2_c, wb2_c};
    float wl1[4] = {wb2_c, wb2_c, wb2_c, wb2_c};
    #pragma unroll
    for (int g = 0; g < 8; g++){
      float wg = w2col[g];
      pk2 a0; a0.u = (unsigned)__shfl((int)hp00, qb | g, 64);
      pk2 a1; a1.u = (unsigned)__shfl((int)hp01, qb | g, 64);
      pk2 b0; b0.u = (unsigned)__shfl((int)hp10, qb | g, 64);
      pk2 b1; b1.u = (unsigned)__shfl((int)hp11, qb | g, 64);
      wl0[0] += (float)a0.h[0]*wg; wl0[1] += (float)a0.h[1]*wg;
      wl0[2] += (float)a1.h[0]*wg; wl0[3] += (float)a1.h[1]*wg;
      wl1[0] += (float)b0.h[0]*wg; wl1[1] += (float)b0.h[1]*wg;
      wl1[2] += (float)b1.h[0]*wg; wl1[3] += (float)b1.h[1]*wg;
    }
    float e0[4], e1[4];
    #pragma unroll
    for (int r = 0; r < 4; r++){
      e0[r] = exp2f(wl0[r]*1.44269504f);
      e1[r] = exp2f(wl1[r]*1.44269504f);
    }
    float sm0 = e0[0]+e0[1]+e0[2]+e0[3];
    float sm1 = e1[0]+e1[1]+e1[2]+e1[3];
    sm0 += __shfl_xor(sm0, 16, 64); sm1 += __shfl_xor(sm1, 16, 64);
    sm0 += __shfl_xor(sm0, 32, 64); sm1 += __shfl_xor(sm1, 32, 64);
    float rn0 = 1.0f/sm0, rn1 = 1.0f/sm1;
    #pragma unroll
    for (int r = 0; r < 4; r++){ e0[r] *= rn0; e1[r] *= rn1; }
    unsigned ep00 = packh(e0[0], e0[1]), ep01 = packh(e0[2], e0[3]);
    unsigned ep10 = packh(e1[0], e1[1]), ep11 = packh(e1[2], e1[3]);

    float ov0[4], ov1[4];
    #pragma unroll
    for (int t = 0; t < 4; t++){
      f32x4 z0 = {0.f,0.f,0.f,0.f}, z1 = {0.f,0.f,0.f,0.f};
      z0 = __builtin_amdgcn_mfma_f32_16x16x32_bf16(h1A[0], pw2f[t][0], z0, 0,0,0);
      z1 = __builtin_amdgcn_mfma_f32_16x16x32_bf16(h1B[0], pw2f[t][0], z1, 0,0,0);
      z0 = __builtin_amdgcn_mfma_f32_16x16x32_bf16(h1A[1], pw2f[t][1], z0, 0,0,0);
      z1 = __builtin_amdgcn_mfma_f32_16x16x32_bf16(h1B[1], pw2f[t][1], z1, 0,0,0);
      int src = qb | (t*2 + ch);
      pk2 wA0; wA0.u = (unsigned)__shfl((int)ep00, src, 64);
      pk2 wA1; wA1.u = (unsigned)__shfl((int)ep01, src, 64);
      pk2 wB0; wB0.u = (unsigned)__shfl((int)ep10, src, 64);
      pk2 wB1; wB1.u = (unsigned)__shfl((int)ep11, src, 64);
      float a = 0.f, bacc = 0.f;
      a += (z0[0] + bf2f(vt0[(q*4+0)*72 + t*16 + c])) * (float)wA0.h[0];
      a += (z0[1] + bf2f(vt0[(q*4+1)*72 + t*16 + c])) * (float)wA0.h[1];
      a += (z0[2] + bf2f(vt0[(q*4+2)*72 + t*16 + c])) * (float)wA1.h[0];
      a += (z0[3] + bf2f(vt0[(q*4+3)*72 + t*16 + c])) * (float)wA1.h[1];
      bacc += (z1[0] + bf2f(vt1[(q*4+0)*72 + t*16 + c])) * (float)wB0.h[0];
      bacc += (z1[1] + bf2f(vt1[(q*4+1)*72 + t*16 + c])) * (float)wB0.h[1];
      bacc += (z1[2] + bf2f(vt1[(q*4+2)*72 + t*16 + c])) * (float)wB1.h[0];
      bacc += (z1[3] + bf2f(vt1[(q*4+3)*72 + t*16 + c])) * (float)wB1.h[1];
      ov0[t] = a; ov1[t] = bacc;
    }
    #pragma unroll
    for (int t = 0; t < 4; t++){
      ov0[t] += __shfl_xor(ov0[t], 16, 64);
      ov1[t] += __shfl_xor(ov1[t], 16, 64);
      ov0[t] += __shfl_xor(ov0[t], 32, 64);
      ov1[t] += __shfl_xor(ov1[t], 32, 64);
      ov0[t] += pb2t[t]; ov1[t] += pb2t[t];
    }
    float s0 = ov0[0], s1 = ov1[0];
    s0 = (q==1) ? ov0[1] : s0;  s1 = (q==1) ? ov1[1] : s1;
    s0 = (q==2) ? ov0[2] : s0;  s1 = (q==2) ? ov1[2] : s1;
    s0 = (q==3) ? ov0[3] : s0;  s1 = (q==3) ? ov1[3] : s1;
    s_tile[(w*8 + 2*i + 0)*66 + l] = s0;
    s_tile[(w*8 + 2*i + 1)*66 + l] = s1;

    iv0 = ivn0; iv1 = ivn1; qp0 = qpn0; qp1 = qpn1;
    cpA0 = cpnA0; cpA1 = cpnA1; cpA2 = cpnA2;
    cpB0 = cpnB0; cpB1 = cpnB1; cpB2 = cpnB2;
  }
  __syncthreads();

  int o0 = tid >> 5, pt = tid & 31;
  int m0 = pbase & (M_-1);
  long outb = ((long)b*64) * M_ + m0 + pt;
  #pragma unroll
  for (int ii = 0; ii < 8; ii++){
    int o = o0*8 + ii;
    out[outb + (long)o*M_] = s_tile[pt*66 + o];
  }
}

extern "C" void kernel_launch(void* const* d_in, const int* in_sizes, int n_in,
                              void* d_out, int out_size, void* d_ws, size_t ws_size,
                              hipStream_t stream) {
  const float* center_pos = (const float*)d_in[0];
  const float* center_fea = (const float*)d_in[1];
  const float* pos        = (const float*)d_in[2];
  const float* fea        = (const float*)d_in[3];
  const int*   idx        = (const int*)d_in[4];
  const float* Wq = (const float*)d_in[5];   const float* bq = (const float*)d_in[6];
  const float* Wk = (const float*)d_in[7];   const float* bk = (const float*)d_in[8];
  const float* Wv = (const float*)d_in[9];   const float* bv = (const float*)d_in[10];
  const float* cpe_w1 = (const float*)d_in[11]; const float* cpe_s = (const float*)d_in[12];
  const float* cpe_b  = (const float*)d_in[13]; const float* cpe_w2 = (const float*)d_in[14];
  const float* cpe_b2 = (const float*)d_in[15];
  const float* pe_w1 = (const float*)d_in[16]; const float* pe_s = (const float*)d_in[17];
  const float* pe_b  = (const float*)d_in[18]; const float* pe_w2 = (const float*)d_in[19];
  const float* pe_b2 = (const float*)d_in[20];
  const float* we_w1 = (const float*)d_in[21]; const float* we_s = (const float*)d_in[22];
  const float* we_b  = (const float*)d_in[23]; const float* we_w2 = (const float*)d_in[24];
  const float* we_b2 = (const float*)d_in[25];

  // ws: xk u16 | xv u16 | qw f32 | bw u16 | cinit f32
  const size_t SZ = (size_t)B_*N_*64;
  u16* xk = (u16*)d_ws;
  u16* xv = xk + SZ;
  float* qwp = (float*)(xv + SZ);
  u16* bwp = (u16*)(qwp + (size_t)B_*M_*8);
  float* cinitp = (float*)(bwp + 2176);
  float* outp = (float*)d_out;

  hipLaunchKernelGGL(setup_kernel, dim3(1), dim3(256), 0, stream,
      Wq, bq, cpe_w2, cpe_b2, we_w1, bwp, cinitp);
  hipLaunchKernelGGL(pre_kernel, dim3(2048), dim3(256), 0, stream,
      center_pos, center_fea, fea, Wk, bk, Wv, bv,
      cpe_w1, cpe_s, cpe_b, bwp, cinitp, xk, xv, qwp);
  hipLaunchKernelGGL(attn_kernel, dim3(2048), dim3(256), 0, stream,
      center_pos, pos, idx, pe_w1, pe_s, pe_b, pe_w2, pe_b2,
      we_w1, we_s, we_b, we_w2, we_b2, xk, xv, qwp, outp);
}